// Round 12
// baseline (200.285 us; speedup 1.0000x reference)
//
#include <hip/hip_runtime.h>

// CellList — all i<j pairs of N atoms, cutoff 5.2. Output: FLOAT32, flat,
// 7P elements, P = N(N-1)/2:
//   [0,P) i | [P,2P) j | [2P,3P) in_cutoff | [3P,6P) diff*mask | [6P,7P) dist
//
// Store-BW bound (528 MB mandatory). Forensics:
//  r6:  nontemporal -> defeats L2 write-merge (988 MB, 2.4 TB/s).
//  r7:  8 pairs/thread -> VGPR 124 -> occupancy -> 155 us.
//  r8:  LDS-densified diff ~neutral: store density NOT the limiter.
//  r9:  persistent blocks ~neutral: dispatch NOT the limiter.
//  r10: phase-split CONFOUNDED (16-stride gather loads) -> 289 us.
//  r11: lane-consecutive loads ~neutral: loads NOT the limiter. 5.2 TB/s flat.
// r12: phase-split with FIXED loads — 5 sequential kernels, each writes ONE
// contiguous region (single global write stream, fill-like DRAM row
// locality). Tests the last open hypothesis for the 5.2 vs 6.9 TB/s gap.

static __device__ __forceinline__ void decode_ij(int p, int N, int twoNm1,
                                                 int& io, int& jo) {
    // rows(i) = i*(2N-1-i)/2; exact int64 disc, f32 sqrt, int correction.
    long long disc_i = (long long)twoNm1 * (long long)twoNm1 - 8LL * (long long)p;
    float sr = __fsqrt_rn((float)disc_i);
    int i = (int)(((float)twoNm1 - sr) * 0.5f);
    if (i < 0) i = 0;
    if (i > N - 2) i = N - 2;
    long long ri = ((long long)i * (long long)(twoNm1 - i)) >> 1;
    while (i < N - 2) {
        long long rn = ((long long)(i + 1) * (long long)(twoNm1 - (i + 1))) >> 1;
        if (rn <= (long long)p) { ++i; ri = rn; } else break;
    }
    while (i > 0 && ri > (long long)p) {
        --i; ri = ((long long)i * (long long)(twoNm1 - i)) >> 1;
    }
    io = i;
    jo = i + 1 + (int)((long long)p - ri);
}

// numpy-exact f32: (dx*dx + dy*dy) + dz*dz, no FMA contraction
static __device__ __forceinline__ float geom(const int* species,
                                             const float* coords, int i, int j,
                                             float& dx, float& dy, float& dz,
                                             float& d) {
    dx = coords[3 * i + 0] - coords[3 * j + 0];
    dy = coords[3 * i + 1] - coords[3 * j + 1];
    dz = coords[3 * i + 2] - coords[3 * j + 2];
    float sq = __fadd_rn(__fadd_rn(__fmul_rn(dx, dx), __fmul_rn(dy, dy)),
                         __fmul_rn(dz, dz));
    d = __fsqrt_rn(sq);
    bool inc = (d <= 5.2f) && (species[i] != -1) && (species[j] != -1);
    return inc ? 1.0f : 0.0f;
}

// ---- indices: write i (WHICH=0) or j (WHICH=1); no loads ----
template <int WHICH>
__global__ __launch_bounds__(256) void k_idx(float* __restrict__ dst,
                                             int N, int P, int ntiles) {
    const int t = threadIdx.x;
    const int twoNm1 = 2 * N - 1;
    for (int tile = blockIdx.x; tile < ntiles; tile += gridDim.x) {
        const int base = tile << 10;
#pragma unroll
        for (int k = 0; k < 4; ++k) {
            const int p = base + (k << 8) + t;   // lane-consecutive pairs
            if (p < P) {
                int i, j; decode_ij(p, N, twoNm1, i, j);
                dst[p] = WHICH ? (float)j : (float)i;
            }
        }
    }
}

// ---- scalar geometry: mask (MODE=0) or dist (MODE=1) ----
template <int MODE>
__global__ __launch_bounds__(256) void k_geo(const int* __restrict__ species,
                                             const float* __restrict__ coords,
                                             float* __restrict__ dst,
                                             int N, int P, int ntiles) {
    const int t = threadIdx.x;
    const int twoNm1 = 2 * N - 1;
    for (int tile = blockIdx.x; tile < ntiles; tile += gridDim.x) {
        const int base = tile << 10;
#pragma unroll
        for (int k = 0; k < 4; ++k) {
            const int p = base + (k << 8) + t;
            if (p < P) {
                int i, j; decode_ij(p, N, twoNm1, i, j);
                float dx, dy, dz, d;
                float m = geom(species, coords, i, j, dx, dy, dz, d);
                dst[p] = MODE ? __fmul_rn(d, m) : m;
            }
        }
    }
}

// ---- diff [P,3]: LDS transpose per 1024-pair tile, dense float4 out ----
__global__ __launch_bounds__(256) void k_diff(const int* __restrict__ species,
                                              const float* __restrict__ coords,
                                              float* __restrict__ dst,
                                              int N, int P, int ntiles) {
    __shared__ float ldsd[3072];            // 1024 pairs x 3 floats
    const int t = threadIdx.x;
    const int twoNm1 = 2 * N - 1;
    for (int tile = blockIdx.x; tile < ntiles; tile += gridDim.x) {
        const int base = tile << 10;
        const bool full = (base + 1024 <= P);
        if (full) {
#pragma unroll
            for (int k = 0; k < 4; ++k) {
                const int p = base + (k << 8) + t;
                int i, j; decode_ij(p, N, twoNm1, i, j);
                float dx, dy, dz, d;
                float m = geom(species, coords, i, j, dx, dy, dz, d);
                const int q = (k << 8) + t;
                ldsd[3 * q + 0] = __fmul_rn(dx, m);
                ldsd[3 * q + 1] = __fmul_rn(dy, m);
                ldsd[3 * q + 2] = __fmul_rn(dz, m);
            }
            __syncthreads();
            const float4* lr = reinterpret_cast<const float4*>(ldsd);
            float4 d0 = lr[t];
            float4 d1 = lr[t + 256];
            float4 d2 = lr[t + 512];
            float* gd = dst + 3 * (size_t)base;
            reinterpret_cast<float4*>(gd)[t]        = d0;
            reinterpret_cast<float4*>(gd + 1024)[t] = d1;
            reinterpret_cast<float4*>(gd + 2048)[t] = d2;
            __syncthreads();
        } else {
            for (int k = 0; k < 4; ++k) {
                const int p = base + (k << 8) + t;
                if (p >= P) continue;
                int i, j; decode_ij(p, N, twoNm1, i, j);
                float dx, dy, dz, d;
                float m = geom(species, coords, i, j, dx, dy, dz, d);
                dst[3 * (size_t)p + 0] = __fmul_rn(dx, m);
                dst[3 * (size_t)p + 1] = __fmul_rn(dy, m);
                dst[3 * (size_t)p + 2] = __fmul_rn(dz, m);
            }
        }
    }
}

extern "C" void kernel_launch(void* const* d_in, const int* in_sizes, int n_in,
                              void* d_out, int out_size, void* d_ws, size_t ws_size,
                              hipStream_t stream) {
    const int*   species = (const int*)d_in[0];
    const float* coords  = (const float*)d_in[1];
    float*       out     = (float*)d_out;
    int N = in_sizes[0];
    long long Pll = (long long)N * (long long)(N - 1) / 2;
    int P = (int)Pll;
    size_t Ps = (size_t)P;

    int ntiles = (int)((Pll + 1023) >> 10);      // 1024 pairs per tile
    int grid = 2048;                              // persistent, dispatch-safe
    if (grid > ntiles) grid = ntiles;
    dim3 g((unsigned)grid), b(256);

    k_idx<0><<<g, b, 0, stream>>>(out,          N, P, ntiles);
    k_idx<1><<<g, b, 0, stream>>>(out + Ps,     N, P, ntiles);
    k_geo<0><<<g, b, 0, stream>>>(species, coords, out + 2 * Ps, N, P, ntiles);
    k_diff  <<<g, b, 0, stream>>>(species, coords, out + 3 * Ps, N, P, ntiles);
    k_geo<1><<<g, b, 0, stream>>>(species, coords, out + 6 * Ps, N, P, ntiles);
}

// Round 13
// 110.496 us; speedup vs baseline: 1.8126x; 1.8126x over previous
//
#include <hip/hip_runtime.h>

// CellList — all i<j pairs of N atoms, cutoff 5.2. Output: FLOAT32, flat,
// 7P elements, P = N(N-1)/2:
//   [0,P) i | [P,2P) j | [2P,3P) in_cutoff | [3P,6P) diff*mask | [6P,7P) dist
//
// Store-BW bound (528 MB mandatory). Forensics ledger:
//  r6:  nontemporal -> defeats L2 write-merge (988 MB, 2.4 TB/s).
//  r7:  8 pairs/thread -> VGPR 124 -> occupancy -> 155 us.
//  r8:  LDS-densified diff ~neutral: store shape NOT the limiter.
//  r9:  persistent strided tiles ~neutral: dispatch NOT the limiter.
//  r10: phase-split w/ gather loads -> 289 us (load-confounded).
//  r11: lane-consecutive loads ~neutral: loads NOT the limiter.
//       r8 vs r11 (4x decode count, same time): decode NOT the limiter.
//  r12: phase-split w/ good loads -> 200 us: compute replicated 5x; split
//       kernels are compute-starved. Multi-stream theory still untested.
// r13: fused kernel, persistent blocks with CONTIGUOUS tile spans — each
// block writes 48 KB contiguous per narrow stream (vs 4 KB), testing DRAM
// row-buffer locality as the cause of the 5.2 vs 6.9 TB/s gap.

__global__ __launch_bounds__(256) void cell_pairs_f32(
    const int* __restrict__ species,
    const float* __restrict__ coords,
    float* __restrict__ out,
    int N, int P, int ntiles, int spb)
{
    __shared__ float ldsd[3072];            // 1024 pairs x 3 floats = 12 KB

    const int t = threadIdx.x;
    const int twoNm1 = 2 * N - 1;
    const size_t Ps = (size_t)P;

    const int t0 = blockIdx.x * spb;        // contiguous span of tiles
    const int t1 = (t0 + spb < ntiles) ? t0 + spb : ntiles;

    for (int tile = t0; tile < t1; ++tile) {
        const int blk = tile << 10;         // 1024 pairs per tile
        const bool full = (blk + 1024 <= P);

        if (full) {
#pragma unroll
            for (int k = 0; k < 4; ++k) {
                const int p = blk + (k << 8) + t;   // lane-consecutive pairs

                // ---- decode (i,j): exact int64 disc, f32 sqrt, correction ----
                long long disc_i = (long long)twoNm1 * (long long)twoNm1
                                 - 8LL * (long long)p;
                float sr = __fsqrt_rn((float)disc_i);
                int i = (int)(((float)twoNm1 - sr) * 0.5f);
                if (i < 0) i = 0;
                if (i > N - 2) i = N - 2;
                long long ri = ((long long)i * (long long)(twoNm1 - i)) >> 1;
                while (i < N - 2) {
                    long long rn = ((long long)(i + 1) * (long long)(twoNm1 - (i + 1))) >> 1;
                    if (rn <= (long long)p) { ++i; ri = rn; } else break;
                }
                while (i > 0 && ri > (long long)p) {
                    --i; ri = ((long long)i * (long long)(twoNm1 - i)) >> 1;
                }
                const int j = i + 1 + (int)((long long)p - ri);

                // ---- pair math (numpy-exact f32, no FMA contraction) ----
                float dx = coords[3 * i + 0] - coords[3 * j + 0];
                float dy = coords[3 * i + 1] - coords[3 * j + 1];
                float dz = coords[3 * i + 2] - coords[3 * j + 2];
                float sq = __fadd_rn(__fadd_rn(__fmul_rn(dx, dx), __fmul_rn(dy, dy)),
                                     __fmul_rn(dz, dz));
                float d  = __fsqrt_rn(sq);
                bool inc = (d <= 5.2f) && (species[i] != -1) && (species[j] != -1);
                float m  = inc ? 1.0f : 0.0f;

                // narrow streams: dword stores, 4B/lane dense
                out[(size_t)p]          = (float)i;
                out[Ps + (size_t)p]     = (float)j;
                out[2 * Ps + (size_t)p] = m;
                out[6 * Ps + (size_t)p] = __fmul_rn(d, m);

                // diff -> LDS (stride-3 words: conflict-free)
                const int q = (k << 8) + t;
                ldsd[3 * q + 0] = __fmul_rn(dx, m);
                ldsd[3 * q + 1] = __fmul_rn(dy, m);
                ldsd[3 * q + 2] = __fmul_rn(dz, m);
            }

            __syncthreads();

            // diff writeback: 3 dense chunks of 1024 floats (float4/lane)
            const float4* lr = reinterpret_cast<const float4*>(ldsd);
            float4 d0 = lr[t];
            float4 d1 = lr[t + 256];
            float4 d2 = lr[t + 512];
            float* gd = out + 3 * Ps + 3 * (size_t)blk;
            reinterpret_cast<float4*>(gd)[t]        = d0;
            reinterpret_cast<float4*>(gd + 1024)[t] = d1;
            reinterpret_cast<float4*>(gd + 2048)[t] = d2;

            __syncthreads();   // protect LDS before next tile overwrites
        } else {
            // partial tail tile (not hit when P % 1024 == 0): scalar path
            for (int k = 0; k < 4; ++k) {
                const int p = blk + (k << 8) + t;
                if (p >= P) continue;
                long long disc_i = (long long)twoNm1 * (long long)twoNm1
                                 - 8LL * (long long)p;
                float sr = __fsqrt_rn((float)disc_i);
                int i = (int)(((float)twoNm1 - sr) * 0.5f);
                if (i < 0) i = 0;
                if (i > N - 2) i = N - 2;
                long long ri = ((long long)i * (long long)(twoNm1 - i)) >> 1;
                while (i < N - 2) {
                    long long rn = ((long long)(i + 1) * (long long)(twoNm1 - (i + 1))) >> 1;
                    if (rn <= (long long)p) { ++i; ri = rn; } else break;
                }
                while (i > 0 && ri > (long long)p) {
                    --i; ri = ((long long)i * (long long)(twoNm1 - i)) >> 1;
                }
                const int j = i + 1 + (int)((long long)p - ri);

                float dx = coords[3 * i + 0] - coords[3 * j + 0];
                float dy = coords[3 * i + 1] - coords[3 * j + 1];
                float dz = coords[3 * i + 2] - coords[3 * j + 2];
                float sq = __fadd_rn(__fadd_rn(__fmul_rn(dx, dx), __fmul_rn(dy, dy)),
                                     __fmul_rn(dz, dz));
                float d  = __fsqrt_rn(sq);
                bool inc = (d <= 5.2f) && (species[i] != -1) && (species[j] != -1);
                float m  = inc ? 1.0f : 0.0f;

                size_t pp = (size_t)p;
                out[pp]                  = (float)i;
                out[Ps + pp]             = (float)j;
                out[2 * Ps + pp]         = m;
                out[3 * Ps + 3 * pp + 0] = __fmul_rn(dx, m);
                out[3 * Ps + 3 * pp + 1] = __fmul_rn(dy, m);
                out[3 * Ps + 3 * pp + 2] = __fmul_rn(dz, m);
                out[6 * Ps + pp]         = __fmul_rn(d, m);
            }
        }
    }
}

extern "C" void kernel_launch(void* const* d_in, const int* in_sizes, int n_in,
                              void* d_out, int out_size, void* d_ws, size_t ws_size,
                              hipStream_t stream) {
    const int*   species = (const int*)d_in[0];
    const float* coords  = (const float*)d_in[1];
    int N = in_sizes[0];
    long long Pll = (long long)N * (long long)(N - 1) / 2;
    int P = (int)Pll;

    int ntiles = (int)((Pll + 1023) >> 10);      // 1024 pairs per tile
    int grid   = 1536;                            // 6 blocks/CU x 256 CU
    if (grid > ntiles) grid = ntiles;
    int spb = (ntiles + grid - 1) / grid;         // contiguous tiles per block

    cell_pairs_f32<<<dim3((unsigned)grid), dim3(256), 0, stream>>>(
        species, coords, (float*)d_out, N, P, ntiles, spb);
}

// Round 14
// 101.456 us; speedup vs baseline: 1.9741x; 1.0891x over previous
//
#include <hip/hip_runtime.h>

// CellList — all i<j pairs of N atoms, cutoff 5.2. Output: FLOAT32, flat,
// 7P elements, P = N(N-1)/2:
//   [0,P)    atom_pairs row i
//   [P,2P)   atom_pairs row j
//   [2P,3P)  in_cutoff (1.0/0.0)
//   [3P,6P)  diff [P,3] = (coords[i]-coords[j]) * in_cutoff
//   [6P,7P)  dist = in_cutoff ? ||coords[i]-coords[j]|| : 0
//
// BEST MEASURED: 101.1 us (r8) = 5.23 TB/s effective for the 528.4 MB
// mandatory output. Forensics ledger (all alternatives tested & rejected):
//  r6:  nontemporal stores -> defeat L2 write-merge (988 MB, 2.4 TB/s).
//  r7:  8 pairs/thread -> VGPR 124 -> occupancy drop -> 155 us.
//  r8:  LDS-densified diff ~neutral vs r4: store shape not limiting.
//  r9:  persistent strided tiles 104 us: dispatch not limiting.
//  r10: phase-split w/ gather loads 289 us (confounded).
//  r11: lane-consecutive loads 102 us: loads/decode not limiting.
//  r12: phase-split w/ good loads 200 us: 5x compute replication loses.
//  r13: contiguous-span persistent 110 us: DRAM row locality not it.
// Conclusion: 5.2 TB/s is this output-shape's practical write ceiling
// (83% of the 6.3 TB/s achievable HBM BW; fill-only kernels do 6.9).

__global__ __launch_bounds__(256) void cell_pairs_f32(
    const int* __restrict__ species,
    const float* __restrict__ coords,
    float* __restrict__ out,
    int N, int P)
{
    __shared__ float ldsd[3072];            // 1024 pairs x 3 floats = 12 KB

    const int t   = threadIdx.x;
    const int blk = blockIdx.x << 10;       // 1024 pairs per block
    if (blk >= P) return;
    const bool full = (blk + 1024 <= P);
    const int p0 = blk + (t << 2);

    // ---- decode (i,j) for first pair p0 (valid when p0 < P) ----
    // rows(i) = i*(2N-1-i)/2; exact int64 disc, f32 sqrt, int correction.
    const int twoNm1 = 2 * N - 1;
    int i = 0, j = 1;
    if (p0 < P) {
        long long disc_i = (long long)twoNm1 * (long long)twoNm1 - 8LL * (long long)p0;
        float sr = __fsqrt_rn((float)disc_i);
        i = (int)(((float)twoNm1 - sr) * 0.5f);
        if (i < 0) i = 0;
        if (i > N - 2) i = N - 2;
        long long ri = ((long long)i * (long long)(twoNm1 - i)) >> 1;
        while (i < N - 2) {
            long long rn = ((long long)(i + 1) * (long long)(twoNm1 - (i + 1))) >> 1;
            if (rn <= (long long)p0) { ++i; ri = rn; } else break;
        }
        while (i > 0 && ri > (long long)p0) {
            --i; ri = ((long long)i * (long long)(twoNm1 - i)) >> 1;
        }
        j = i + 1 + (int)((long long)p0 - ri);
    }

    if (full) {
        float cix = coords[3 * i + 0];
        float ciy = coords[3 * i + 1];
        float ciz = coords[3 * i + 2];
        int   si  = species[i];

        float iv[4], jv[4], cv[4], sv[4], dv[12];
#pragma unroll 4
        for (int k = 0; k < 4; ++k) {
            if (j >= N) {
                ++i; j = i + 1;
                cix = coords[3 * i + 0];
                ciy = coords[3 * i + 1];
                ciz = coords[3 * i + 2];
                si  = species[i];
            }
            float dx = cix - coords[3 * j + 0];
            float dy = ciy - coords[3 * j + 1];
            float dz = ciz - coords[3 * j + 2];
            // numpy-exact f32: (dx*dx + dy*dy) + dz*dz, no FMA contraction
            float sq = __fadd_rn(__fadd_rn(__fmul_rn(dx, dx), __fmul_rn(dy, dy)),
                                 __fmul_rn(dz, dz));
            float d  = __fsqrt_rn(sq);
            bool inc = (d <= 5.2f) && (si != -1) && (species[j] != -1);
            float m  = inc ? 1.0f : 0.0f;

            iv[k] = (float)i;
            jv[k] = (float)j;
            cv[k] = m;
            sv[k] = __fmul_rn(d, m);
            dv[3 * k + 0] = __fmul_rn(dx, m);
            dv[3 * k + 1] = __fmul_rn(dy, m);
            dv[3 * k + 2] = __fmul_rn(dz, m);
            ++j;
        }

        // diff -> LDS (dense: 48B/lane, ds_write_b128 x3)
        float4* lw = reinterpret_cast<float4*>(&ldsd[12 * t]);
        lw[0] = make_float4(dv[0], dv[1], dv[2],  dv[3]);
        lw[1] = make_float4(dv[4], dv[5], dv[6],  dv[7]);
        lw[2] = make_float4(dv[8], dv[9], dv[10], dv[11]);

        // narrow streams direct (dense: 16B/lane stride 16B)
        const size_t Ps = (size_t)P;
        *reinterpret_cast<float4*>(out + (size_t)p0)
            = make_float4(iv[0], iv[1], iv[2], iv[3]);
        *reinterpret_cast<float4*>(out + Ps + (size_t)p0)
            = make_float4(jv[0], jv[1], jv[2], jv[3]);
        *reinterpret_cast<float4*>(out + 2 * Ps + (size_t)p0)
            = make_float4(cv[0], cv[1], cv[2], cv[3]);
        *reinterpret_cast<float4*>(out + 6 * Ps + (size_t)p0)
            = make_float4(sv[0], sv[1], sv[2], sv[3]);

        __syncthreads();

        // diff writeback: 3 dense chunks of 1024 floats
        const float4* lr = reinterpret_cast<const float4*>(ldsd);
        float4 d0 = lr[t];
        float4 d1 = lr[t + 256];
        float4 d2 = lr[t + 512];
        float* gd = out + 3 * Ps + 3 * (size_t)blk;
        reinterpret_cast<float4*>(gd)[t]        = d0;
        reinterpret_cast<float4*>(gd + 1024)[t] = d1;
        reinterpret_cast<float4*>(gd + 2048)[t] = d2;
    } else {
        // partial tail block (not hit when P % 1024 == 0): scalar, no barrier
        const size_t Ps = (size_t)P;
        for (int k = 0; k < 4; ++k) {
            int p = p0 + k;
            if (p >= P) break;
            if (j >= N) { ++i; j = i + 1; }
            float dx = coords[3 * i + 0] - coords[3 * j + 0];
            float dy = coords[3 * i + 1] - coords[3 * j + 1];
            float dz = coords[3 * i + 2] - coords[3 * j + 2];
            float sq = __fadd_rn(__fadd_rn(__fmul_rn(dx, dx), __fmul_rn(dy, dy)),
                                 __fmul_rn(dz, dz));
            float d  = __fsqrt_rn(sq);
            bool inc = (d <= 5.2f) && (species[i] != -1) && (species[j] != -1);
            float m  = inc ? 1.0f : 0.0f;
            size_t pp = (size_t)p;
            out[pp]                  = (float)i;
            out[Ps + pp]             = (float)j;
            out[2 * Ps + pp]         = m;
            out[3 * Ps + 3 * pp + 0] = __fmul_rn(dx, m);
            out[3 * Ps + 3 * pp + 1] = __fmul_rn(dy, m);
            out[3 * Ps + 3 * pp + 2] = __fmul_rn(dz, m);
            out[6 * Ps + pp]         = __fmul_rn(d, m);
            ++j;
        }
    }
}

extern "C" void kernel_launch(void* const* d_in, const int* in_sizes, int n_in,
                              void* d_out, int out_size, void* d_ws, size_t ws_size,
                              hipStream_t stream) {
    const int*   species = (const int*)d_in[0];
    const float* coords  = (const float*)d_in[1];
    int N = in_sizes[0];
    long long Pll = (long long)N * (long long)(N - 1) / 2;
    int P = (int)Pll;

    long long blocks = (Pll + 1023) >> 10;   // 1024 pairs per block
    cell_pairs_f32<<<dim3((unsigned)blocks), dim3(256), 0, stream>>>(
        species, coords, (float*)d_out, N, P);
}